// Round 1
// baseline (119.538 us; speedup 1.0000x reference)
//
#include <hip/hip_runtime.h>
#include <hip/hip_bf16.h>
#include <math.h>

// ---------------------------------------------------------------------------
// HighFreqSuppressionLoss: per image gray = (0.299R+0.587G+0.114B + 1)/2,
// F = fft2(gray), psd = mean over high-freq region of log10(|F|^2 + 1e-10),
// loss = mean_b |psd_gen - psd_tgt|.
// Unshifted mask: EXCLUDE element iff lowband(kx) && lowband(ky),
// lowband(k) := k < 64 || k >= 448.   mask count = 512^2 - 128^2 = 245760.
// FFT: 512 = 8^3 DIF radix-8, 64 lanes/FFT, 8 float2 regs/lane.
// Output stored digit-reversed: stored s -> true k = ((s&7)<<6)|(s&56)|(s>>6).
// => lowband(k(s)) <=> (s&7)==0 || (s&7)==7.
// ---------------------------------------------------------------------------

__device__ double g_partials[64 * 64 * 4];              // [img][cb][wave]
__device__ __align__(16) float2 g_wsfall[512 * 512];    // fallback if ws tiny

__device__ __forceinline__ float2 cadd(float2 a, float2 b){ return make_float2(a.x+b.x, a.y+b.y); }
__device__ __forceinline__ float2 csub(float2 a, float2 b){ return make_float2(a.x-b.x, a.y-b.y); }
__device__ __forceinline__ float2 cmul(float2 a, float2 b){
  return make_float2(fmaf(a.x, b.x, -(a.y*b.y)), fmaf(a.x, b.y, a.y*b.x));
}
__device__ __forceinline__ float2 mul_mi(float2 a){ return make_float2(a.y, -a.x); } // *( -i )

// 8-point DFT, natural order in/out (verified against w8^k table).
__device__ __forceinline__ void fft8(float2 v[8]){
  const float S = 0.70710678118654752440f;
  float2 c0=cadd(v[0],v[4]), c1=cadd(v[1],v[5]), c2=cadd(v[2],v[6]), c3=cadd(v[3],v[7]);
  float2 d0=csub(v[0],v[4]);
  float2 t1=csub(v[1],v[5]);
  float2 d1=make_float2(S*(t1.x+t1.y), S*(t1.y-t1.x));   // *(S,-S)  = w8^1
  float2 d2=mul_mi(csub(v[2],v[6]));                     // *(-i)    = w8^2
  float2 t3=csub(v[3],v[7]);
  float2 d3=make_float2(S*(t3.y-t3.x), -S*(t3.x+t3.y));  // *(-S,-S) = w8^3
  float2 e0=cadd(c0,c2), e1=cadd(c1,c3), f0=csub(c0,c2), f1=mul_mi(csub(c1,c3));
  float2 g0=cadd(d0,d2), g1=cadd(d1,d3), h0=csub(d0,d2), h1=mul_mi(csub(d1,d3));
  v[0]=cadd(e0,e1); v[4]=csub(e0,e1);
  v[2]=cadd(f0,f1); v[6]=csub(f0,f1);
  v[1]=cadd(g0,g1); v[5]=csub(g0,g1);
  v[3]=cadd(h0,h1); v[7]=csub(h0,h1);
}

// v[m] *= w^m with w = exp(i*ang)
__device__ __forceinline__ void twiddle8(float2 v[8], float ang){
  float sn, cs;
  sincosf(ang, &sn, &cs);
  float2 w = make_float2(cs, sn);
  float2 wp = w;
  v[1] = cmul(v[1], wp);
  #pragma unroll
  for (int m = 2; m < 8; ++m){ wp = cmul(wp, w); v[m] = cmul(v[m], wp); }
}

// XOR swizzle for exchange buffer indices: i ^ (2 * ((i>>6)&7)); banks <= 4-way.
__device__ __forceinline__ int exsw(int i){ return i ^ ((i >> 5) & 0xE); }

// 512-pt DIF FFT across one wave. lane t holds x[t + 64*j] on entry.
// On exit reg j of lane t holds X[true k], stored index s = 8*t + j,
// true k = 64*j + 8*(t&7) + (t>>3).
// ex: per-wave 512-entry float2 LDS exchange buffer. Contains __syncthreads.
__device__ __forceinline__ void fft512(float2 v[8], float2* ex, int t){
  const float TW = -6.28318530717958647692f;
  fft8(v);
  twiddle8(v, TW * (float)t * (1.0f/512.0f));
  __syncthreads();
  #pragma unroll
  for (int m = 0; m < 8; ++m) ex[exsw(m*64 + t)] = v[m];
  __syncthreads();
  const int q = t >> 3, n = t & 7;
  #pragma unroll
  for (int j = 0; j < 8; ++j) v[j] = ex[exsw(q*64 + n + 8*j)];
  fft8(v);
  twiddle8(v, TW * (float)n * (1.0f/64.0f));
  __syncthreads();
  #pragma unroll
  for (int m = 0; m < 8; ++m) ex[exsw(q*64 + m*8 + n)] = v[m];
  __syncthreads();
  #pragma unroll
  for (int j = 0; j < 8; ++j) v[j] = ex[exsw(q*64 + n*8 + j)];
  fft8(v);
}

// Stage 1: row FFTs. Block = 256 thr = 4 waves, one row per wave.
// Grid = nimg * 128.  ws layout: [img_local][y][c_stored] complex, row-major.
__global__ __launch_bounds__(256)
void k_rowfft(const float* __restrict__ gen, const float* __restrict__ tgt,
              float2* ws, int img0){
  float2* w = ws ? ws : g_wsfall;
  const int wg   = blockIdx.x;
  const int imgl = wg >> 7;
  const int rg   = wg & 127;
  const int img  = img0 + imgl;
  const int wave = threadIdx.x >> 6, t = threadIdx.x & 63;
  const int y    = rg*4 + wave;
  const float* src = (img < 32) ? gen : tgt;
  const int b = img & 31;
  const float* base = src + (size_t)b * 3 * 262144 + (size_t)y * 512;

  __shared__ float2 ex_all[4][512];
  float2* ex = ex_all[wave];

  float2 v[8];
  #pragma unroll
  for (int j = 0; j < 8; ++j){
    const int x = t + 64*j;
    float r  = base[x];
    float g  = base[262144 + x];
    float bl = base[524288 + x];
    float gray = fmaf(0.299f, r, fmaf(0.587f, g, 0.114f * bl));
    gray = (gray + 1.0f) * 0.5f;
    v[j] = make_float2(gray, 0.0f);
  }
  fft512(v, ex, t);
  // lane t holds stored columns 8t..8t+7 -> 64B contiguous, coalesced store
  float4* dst = (float4*)(w + ((size_t)imgl * 512 + y) * 512 + 8*t);
  const float4* pv = (const float4*)v;
  #pragma unroll
  for (int j = 0; j < 4; ++j) dst[j] = pv[j];
}

// Stage 2: column FFTs + masked log10 reduction.
// Block = 256 thr = 4 waves, 8 columns per block (each wave 2 cols serially).
// Grid = nimg * 64.
__global__ __launch_bounds__(256)
void k_colfft(const float2* ws, int img0){
  const float2* w = ws ? ws : (const float2*)g_wsfall;
  const int wg   = blockIdx.x;
  const int imgl = wg >> 6;
  const int cb   = wg & 63;
  const int img  = img0 + imgl;
  const int c0   = cb * 8;
  const int tid  = threadIdx.x;
  const int wave = tid >> 6, t = tid & 63;

  __shared__ float2 tile[512 * 9];     // [y][8 cols + 1 pad]
  __shared__ float2 ex_all[4][512];
  float2* ex = ex_all[wave];

  // Load the 8-column stripe: per row 64B contiguous (4 float4).
  const float4* src = (const float4*)(w + (size_t)imgl * 262144);
  #pragma unroll
  for (int it = 0; it < 8; ++it){
    const int idx = tid + 256*it;      // 0..2047
    const int y = idx >> 2, qq = idx & 3;
    float4 d = src[(size_t)(y * 512 + c0) / 2 + qq];
    tile[y*9 + 2*qq]     = make_float2(d.x, d.y);
    tile[y*9 + 2*qq + 1] = make_float2(d.z, d.w);
  }
  __syncthreads();

  double acc = 0.0;
  for (int ci = 0; ci < 2; ++ci){
    const int cl = wave*2 + ci;
    const int c  = c0 + cl;
    float2 v[8];
    #pragma unroll
    for (int j = 0; j < 8; ++j) v[j] = tile[(t + 64*j)*9 + cl];
    fft512(v, ex, t);
    const bool lowx = ((c & 7) == 0) | ((c & 7) == 7);
    #pragma unroll
    for (int j = 0; j < 8; ++j){
      if (lowx & ((j == 0) | (j == 7))) continue;      // excluded low-low block
      float m2 = fmaf(v[j].x, v[j].x, fmaf(v[j].y, v[j].y, 1e-10f));
      acc += (double)log10f(m2);
    }
  }
  // deterministic wave reduce
  #pragma unroll
  for (int off = 32; off; off >>= 1) acc += __shfl_down(acc, off);
  if (t == 0) g_partials[((size_t)img * 64 + cb) * 4 + wave] = acc;
}

// Final: psd per image, L1 over batch.
__global__ __launch_bounds__(256)
void k_finish(float* __restrict__ out){
  const int tid = threadIdx.x;
  const int img = tid >> 2, part = tid & 3;
  const double* p = g_partials + (size_t)img * 256 + part * 64;
  double s = 0.0;
  #pragma unroll 4
  for (int k = 0; k < 64; ++k) s += p[k];
  __shared__ double sm[256];
  sm[tid] = s;
  __syncthreads();
  if ((tid & 3) == 0){
    double tot = sm[tid] + sm[tid+1] + sm[tid+2] + sm[tid+3];
    sm[tid] = tot * (1.0 / 245760.0);          // psd[img]
  }
  __syncthreads();
  if (tid < 64){
    double d = (tid < 32) ? fabs(sm[tid*4] - sm[(tid+32)*4]) : 0.0;
    #pragma unroll
    for (int off = 32; off; off >>= 1) d += __shfl_down(d, off);
    if (tid == 0) out[0] = (float)(d * (1.0 / 32.0));
  }
}

extern "C" void kernel_launch(void* const* d_in, const int* in_sizes, int n_in,
                              void* d_out, int out_size, void* d_ws, size_t ws_size,
                              hipStream_t stream){
  (void)in_sizes; (void)n_in; (void)out_size;
  const float* gen = (const float*)d_in[0];
  const float* tgt = (const float*)d_in[1];
  float* out = (float*)d_out;

  const size_t per_img = (size_t)512 * 512 * sizeof(float2);   // 2 MiB
  int chunk = (int)(ws_size / per_img);
  float2* wsp = (float2*)d_ws;
  if (chunk < 1){ chunk = 1; wsp = nullptr; }   // use static fallback buffer
  if (chunk > 64) chunk = 64;

  for (int i0 = 0; i0 < 64; i0 += chunk){
    const int n = (64 - i0 < chunk) ? (64 - i0) : chunk;
    k_rowfft<<<dim3(n * 128), dim3(256), 0, stream>>>(gen, tgt, wsp, i0);
    k_colfft<<<dim3(n * 64), dim3(256), 0, stream>>>(wsp, i0);
  }
  k_finish<<<dim3(1), dim3(256), 0, stream>>>(out);
}

// Round 2
// 106.403 us; speedup vs baseline: 1.1234x; 1.1234x over previous
//
#include <hip/hip_runtime.h>
#include <hip/hip_bf16.h>
#include <math.h>

// ---------------------------------------------------------------------------
// HighFreqSuppressionLoss: per image gray = (0.299R+0.587G+0.114B + 1)/2,
// F = fft2(gray), psd = mean over high-freq region of log10(|F|^2 + 1e-10),
// loss = mean_b |psd_gen - psd_tgt|.
// Unshifted mask: EXCLUDE element iff lowband(kx) && lowband(ky),
// lowband(k) := k < 64 || k >= 448.   mask count = 512^2 - 128^2 = 245760.
// FFT: 512 = 8^3 DIF radix-8, 64 lanes/FFT, 8 float2 regs/lane.
// Reg j of lane t holds stored index s = 8t + j; true k = ((s&7)<<6)|(s&56)|(s>>6).
// lowband(k(s)) <=> (s&7)==0 || (s&7)==7.
// ws layout (stage1 out): position p = j*64 + t holds stored s = 8t + j
//   -> every stage-1 store instruction is 512B wave-contiguous.
//   position p has (s&7) = p>>6, so lowband <=> (p>>6)==0 || (p>>6)==7.
// ---------------------------------------------------------------------------

__device__ double g_partials[64 * 64 * 4];              // [img][cb][wave]
__device__ __align__(16) float2 g_wsfall[512 * 512];    // fallback if ws tiny

__device__ __forceinline__ float2 cadd(float2 a, float2 b){ return make_float2(a.x+b.x, a.y+b.y); }
__device__ __forceinline__ float2 csub(float2 a, float2 b){ return make_float2(a.x-b.x, a.y-b.y); }
__device__ __forceinline__ float2 cmul(float2 a, float2 b){
  return make_float2(fmaf(a.x, b.x, -(a.y*b.y)), fmaf(a.x, b.y, a.y*b.x));
}
__device__ __forceinline__ float2 mul_mi(float2 a){ return make_float2(a.y, -a.x); } // *( -i )

// 8-point DFT, natural order in/out.
__device__ __forceinline__ void fft8(float2 v[8]){
  const float S = 0.70710678118654752440f;
  float2 c0=cadd(v[0],v[4]), c1=cadd(v[1],v[5]), c2=cadd(v[2],v[6]), c3=cadd(v[3],v[7]);
  float2 d0=csub(v[0],v[4]);
  float2 t1=csub(v[1],v[5]);
  float2 d1=make_float2(S*(t1.x+t1.y), S*(t1.y-t1.x));   // *(S,-S)  = w8^1
  float2 d2=mul_mi(csub(v[2],v[6]));                     // *(-i)    = w8^2
  float2 t3=csub(v[3],v[7]);
  float2 d3=make_float2(S*(t3.y-t3.x), -S*(t3.x+t3.y));  // *(-S,-S) = w8^3
  float2 e0=cadd(c0,c2), e1=cadd(c1,c3), f0=csub(c0,c2), f1=mul_mi(csub(c1,c3));
  float2 g0=cadd(d0,d2), g1=cadd(d1,d3), h0=csub(d0,d2), h1=mul_mi(csub(d1,d3));
  v[0]=cadd(e0,e1); v[4]=csub(e0,e1);
  v[2]=cadd(f0,f1); v[6]=csub(f0,f1);
  v[1]=cadd(g0,g1); v[5]=csub(g0,g1);
  v[3]=cadd(h0,h1); v[7]=csub(h0,h1);
}

// v[m] *= w^m with w = exp(i*ang); |ang| < 0.8 rad -> fast sincos fine.
__device__ __forceinline__ void twiddle8(float2 v[8], float ang){
  float sn, cs;
  __sincosf(ang, &sn, &cs);
  float2 w = make_float2(cs, sn);
  float2 wp = w;
  v[1] = cmul(v[1], wp);
  #pragma unroll
  for (int m = 2; m < 8; ++m){ wp = cmul(wp, w); v[m] = cmul(v[m], wp); }
}

// Pad: 1 extra float per 8 -> all four exchange phases are <=2-way banked (free).
__device__ __forceinline__ int padi(int i){ return i + (i >> 3); }

// Wave-internal LDS fence: the exchange is cross-LANE but intra-wave, so a
// block barrier is overkill. "memory" clobber stops compiler reordering;
// sched_barrier stops post-RA hoisting (guide rule #18).
__device__ __forceinline__ void lds_fence(){
  asm volatile("s_waitcnt lgkmcnt(0)" ::: "memory");
  __builtin_amdgcn_sched_barrier(0);
}

// 512-pt DIF FFT across one wave. Lane t holds x[t + 64*j] on entry.
// On exit reg j of lane t holds stored index s = 8*t + j.
// re/im: per-wave 576-float LDS exchange buffers. NO block barriers.
__device__ __forceinline__ void fft512(float2 v[8], float* re, float* im, int t){
  const float TW = -6.28318530717958647692f;
  fft8(v);
  twiddle8(v, TW * (float)t * (1.0f/512.0f));
  lds_fence();                                   // prior reads (if any) drained
  #pragma unroll
  for (int m = 0; m < 8; ++m){ int a = padi(m*64 + t); re[a] = v[m].x; im[a] = v[m].y; }
  lds_fence();
  const int q = t >> 3, n = t & 7;
  #pragma unroll
  for (int j = 0; j < 8; ++j){ int a = padi(q*64 + n + 8*j); v[j].x = re[a]; v[j].y = im[a]; }
  fft8(v);
  twiddle8(v, TW * (float)n * (1.0f/64.0f));
  lds_fence();                                   // phase-1 reads drained before overwrite
  #pragma unroll
  for (int m = 0; m < 8; ++m){ int a = padi(q*64 + m*8 + n); re[a] = v[m].x; im[a] = v[m].y; }
  lds_fence();
  #pragma unroll
  for (int j = 0; j < 8; ++j){ int a = padi(q*64 + n*8 + j); v[j].x = re[a]; v[j].y = im[a]; }
  fft8(v);
}

// Stage 1: row FFTs. Block = 256 thr = 4 waves, one row per wave.
// Grid = nimg * 128.  ws: [img_local][y][p] complex, p = j*64 + t.
__global__ __launch_bounds__(256)
void k_rowfft(const float* __restrict__ gen, const float* __restrict__ tgt,
              float2* ws, int img0){
  float2* w = ws ? ws : g_wsfall;
  const int wg   = blockIdx.x;
  const int imgl = wg >> 7;
  const int rg   = wg & 127;
  const int img  = img0 + imgl;
  const int wave = threadIdx.x >> 6, t = threadIdx.x & 63;
  const int y    = rg*4 + wave;
  const float* src = (img < 32) ? gen : tgt;
  const int b = img & 31;
  const float* base = src + (size_t)b * 3 * 262144 + (size_t)y * 512;

  __shared__ float re_all[4][576], im_all[4][576];
  float* re = re_all[wave];
  float* im = im_all[wave];

  float2 v[8];
  #pragma unroll
  for (int j = 0; j < 8; ++j){
    const int x = t + 64*j;
    float r  = base[x];
    float g  = base[262144 + x];
    float bl = base[524288 + x];
    float gray = fmaf(0.299f, r, fmaf(0.587f, g, 0.114f * bl));
    gray = (gray + 1.0f) * 0.5f;
    v[j] = make_float2(gray, 0.0f);
  }
  fft512(v, re, im, t);
  // permuted layout: reg j -> position j*64 + t  => 512B contiguous per store instr
  float2* dst = w + ((size_t)imgl * 512 + y) * 512;
  #pragma unroll
  for (int j = 0; j < 8; ++j) dst[j*64 + t] = v[j];
}

// Stage 2: column FFTs + masked log10 reduction.
// Block = 256 thr = 4 waves, 8 positions per block (each wave 2 serially).
// Grid = nimg * 64.
__global__ __launch_bounds__(256)
void k_colfft(const float2* ws, int img0){
  const float2* w = ws ? ws : (const float2*)g_wsfall;
  const int wg   = blockIdx.x;
  const int imgl = wg >> 6;
  const int cb   = wg & 63;
  const int img  = img0 + imgl;
  const int c0   = cb * 8;
  const int tid  = threadIdx.x;
  const int wave = tid >> 6, t = tid & 63;

  __shared__ float2 tile[8 * 521];     // transposed: [col][y], pad 521
  __shared__ float re_all[4][576], im_all[4][576];
  float* re = re_all[wave];
  float* im = im_all[wave];

  // Load the 8-position stripe: per row 64B contiguous (4 float4).
  const float4* src = (const float4*)(w + (size_t)imgl * 262144);
  #pragma unroll
  for (int it = 0; it < 8; ++it){
    const int idx = tid + 256*it;      // 0..2047
    const int y = idx >> 2, qq = idx & 3;
    float4 d = src[(size_t)(y * 512 + c0) / 2 + qq];
    tile[(2*qq)   * 521 + y] = make_float2(d.x, d.y);
    tile[(2*qq+1) * 521 + y] = make_float2(d.z, d.w);
  }
  __syncthreads();                     // tile is block-shared: keep this one

  // position block: all 8 positions share p>>6 = cb>>3  -> uniform mask bit
  const bool lowx = ((cb >> 3) == 0) | ((cb >> 3) == 7);

  double acc = 0.0;
  for (int ci = 0; ci < 2; ++ci){
    const int cl = wave*2 + ci;
    float2 v[8];
    #pragma unroll
    for (int j = 0; j < 8; ++j) v[j] = tile[cl*521 + t + 64*j];
    fft512(v, re, im, t);
    #pragma unroll
    for (int j = 0; j < 8; ++j){
      if (lowx & ((j == 0) | (j == 7))) continue;      // excluded low-low block
      float m2 = fmaf(v[j].x, v[j].x, fmaf(v[j].y, v[j].y, 1e-10f));
      acc += (double)log10f(m2);
    }
  }
  // deterministic wave reduce
  #pragma unroll
  for (int off = 32; off; off >>= 1) acc += __shfl_down(acc, off);
  if (t == 0) g_partials[((size_t)img * 64 + cb) * 4 + wave] = acc;
}

// Final: psd per image, L1 over batch.
__global__ __launch_bounds__(256)
void k_finish(float* __restrict__ out){
  const int tid = threadIdx.x;
  const int img = tid >> 2, part = tid & 3;
  const double* p = g_partials + (size_t)img * 256 + part * 64;
  double s = 0.0;
  #pragma unroll 4
  for (int k = 0; k < 64; ++k) s += p[k];
  __shared__ double sm[256];
  sm[tid] = s;
  __syncthreads();
  if ((tid & 3) == 0){
    double tot = sm[tid] + sm[tid+1] + sm[tid+2] + sm[tid+3];
    sm[tid] = tot * (1.0 / 245760.0);          // psd[img]
  }
  __syncthreads();
  if (tid < 64){
    double d = (tid < 32) ? fabs(sm[tid*4] - sm[(tid+32)*4]) : 0.0;
    #pragma unroll
    for (int off = 32; off; off >>= 1) d += __shfl_down(d, off);
    if (tid == 0) out[0] = (float)(d * (1.0 / 32.0));
  }
}

extern "C" void kernel_launch(void* const* d_in, const int* in_sizes, int n_in,
                              void* d_out, int out_size, void* d_ws, size_t ws_size,
                              hipStream_t stream){
  (void)in_sizes; (void)n_in; (void)out_size;
  const float* gen = (const float*)d_in[0];
  const float* tgt = (const float*)d_in[1];
  float* out = (float*)d_out;

  const size_t per_img = (size_t)512 * 512 * sizeof(float2);   // 2 MiB
  int chunk = (int)(ws_size / per_img);
  float2* wsp = (float2*)d_ws;
  if (chunk < 1){ chunk = 1; wsp = nullptr; }   // use static fallback buffer
  if (chunk > 64) chunk = 64;

  for (int i0 = 0; i0 < 64; i0 += chunk){
    const int n = (64 - i0 < chunk) ? (64 - i0) : chunk;
    k_rowfft<<<dim3(n * 128), dim3(256), 0, stream>>>(gen, tgt, wsp, i0);
    k_colfft<<<dim3(n * 64), dim3(256), 0, stream>>>(wsp, i0);
  }
  k_finish<<<dim3(1), dim3(256), 0, stream>>>(out);
}

// Round 4
// 76.227 us; speedup vs baseline: 1.5682x; 1.3959x over previous
//
#include <hip/hip_runtime.h>
#include <hip/hip_bf16.h>
#include <math.h>

// ---------------------------------------------------------------------------
// HighFreqSuppressionLoss, real-packed rows + Hermitian-halved columns.
// gray = (0.299R+0.587G+0.114B+1)/2; F = fft2(gray);
// loss = mean_b | mean_M log10(|F_gen|^2+eps) - mean_M log10(|F_tgt|^2+eps) |
// Mask excludes (kx,ky) iff lowband(kx)&&lowband(ky); lowband: k<64||k>=448.
//
// Stage 1: pack rows (2p,2p+1) as z = a+ib, one 512-pt FFT per pair, store in
//   TRUE FREQUENCY ORDER: ws[img][pair p][kx], kx = 64j + 8(t&7) + (t>>3)
//   (reg j of lane t holds stored s=8t+j whose true freq is that kx).
//   Each store instr covers one aligned 512B segment, lane-permuted: coalesced.
// Stage 2 (process kx = 0..256 only; Hermitian PSD symmetry covers the rest):
//   A_p = Z_p[kx], B_p = conj(Z_p[(512-kx)&511]);
//   f[2p] = (A+B)/2, f[2p+1] = -i(A-B)/2;  column FFT over y of f.
//   Element weight for accumulated log10|F[ky,kx]|^2:
//     base = (kx==0||kx==256) ? 1 : 2          (self-mirror cols counted once)
//     - [kx<=63]          * [ky in S ]         (own column lowband)
//     - [1<=kx<=64]       * [ky in S']         (mirror column lowband)
//   S  = {k<64 || k>=448}  <=> j==0 || j==7
//   S' = {k<=64 || k>=449} <=> j==0 || (j==1&&t==0) || (j==7&&t!=0)
//   (ky = 64j + 8(t&7) + (t>>3); verified weight totals = 245760.)
// ---------------------------------------------------------------------------

__device__ double g_partials[64 * 33 * 4];              // [img][blk][wave]
__device__ __align__(16) float2 g_wsfall[256 * 512];    // 1-image fallback

__device__ __forceinline__ float2 cadd(float2 a, float2 b){ return make_float2(a.x+b.x, a.y+b.y); }
__device__ __forceinline__ float2 csub(float2 a, float2 b){ return make_float2(a.x-b.x, a.y-b.y); }
__device__ __forceinline__ float2 cmul(float2 a, float2 b){
  return make_float2(fmaf(a.x, b.x, -(a.y*b.y)), fmaf(a.x, b.y, a.y*b.x));
}
__device__ __forceinline__ float2 mul_mi(float2 a){ return make_float2(a.y, -a.x); } // *(-i)

__device__ __forceinline__ void fft8(float2 v[8]){
  const float S = 0.70710678118654752440f;
  float2 c0=cadd(v[0],v[4]), c1=cadd(v[1],v[5]), c2=cadd(v[2],v[6]), c3=cadd(v[3],v[7]);
  float2 d0=csub(v[0],v[4]);
  float2 t1=csub(v[1],v[5]);
  float2 d1=make_float2(S*(t1.x+t1.y), S*(t1.y-t1.x));   // *w8^1
  float2 d2=mul_mi(csub(v[2],v[6]));                     // *w8^2
  float2 t3=csub(v[3],v[7]);
  float2 d3=make_float2(S*(t3.y-t3.x), -S*(t3.x+t3.y));  // *w8^3
  float2 e0=cadd(c0,c2), e1=cadd(c1,c3), f0=csub(c0,c2), f1=mul_mi(csub(c1,c3));
  float2 g0=cadd(d0,d2), g1=cadd(d1,d3), h0=csub(d0,d2), h1=mul_mi(csub(d1,d3));
  v[0]=cadd(e0,e1); v[4]=csub(e0,e1);
  v[2]=cadd(f0,f1); v[6]=csub(f0,f1);
  v[1]=cadd(g0,g1); v[5]=csub(g0,g1);
  v[3]=cadd(h0,h1); v[7]=csub(h0,h1);
}

__device__ __forceinline__ void twiddle8(float2 v[8], float ang){
  float sn, cs;
  __sincosf(ang, &sn, &cs);
  float2 w = make_float2(cs, sn);
  float2 wp = w;
  v[1] = cmul(v[1], wp);
  #pragma unroll
  for (int m = 2; m < 8; ++m){ wp = cmul(wp, w); v[m] = cmul(v[m], wp); }
}

__device__ __forceinline__ int padi(int i){ return i + (i >> 3); }

// Wave-internal LDS fence (exchange is intra-wave; no block barrier needed).
__device__ __forceinline__ void lds_fence(){
  asm volatile("s_waitcnt lgkmcnt(0)" ::: "memory");
  __builtin_amdgcn_sched_barrier(0);
}

// 512-pt DIF FFT across one wave. Lane t holds x[t+64j] on entry.
// Exit: reg j of lane t = stored s = 8t+j, true freq 64j + 8(t&7) + (t>>3).
__device__ __forceinline__ void fft512(float2 v[8], float* re, float* im, int t){
  const float TW = -6.28318530717958647692f;
  fft8(v);
  twiddle8(v, TW * (float)t * (1.0f/512.0f));
  lds_fence();
  #pragma unroll
  for (int m = 0; m < 8; ++m){ int a = padi(m*64 + t); re[a] = v[m].x; im[a] = v[m].y; }
  lds_fence();
  const int q = t >> 3, n = t & 7;
  #pragma unroll
  for (int j = 0; j < 8; ++j){ int a = padi(q*64 + n + 8*j); v[j].x = re[a]; v[j].y = im[a]; }
  fft8(v);
  twiddle8(v, TW * (float)n * (1.0f/64.0f));
  lds_fence();
  #pragma unroll
  for (int m = 0; m < 8; ++m){ int a = padi(q*64 + m*8 + n); re[a] = v[m].x; im[a] = v[m].y; }
  lds_fence();
  #pragma unroll
  for (int j = 0; j < 8; ++j){ int a = padi(q*64 + n*8 + j); v[j].x = re[a]; v[j].y = im[a]; }
  fft8(v);
}

#define GRAY1(r,g,b) ((fmaf(0.299f,(r), fmaf(0.587f,(g), 0.114f*(b))) + 1.0f)*0.5f)

// Stage 1: packed row-pair FFTs. Block 256 thr = 4 waves = 4 pairs.
// Grid = nimg * 64.  ws: [img_local][pair][kx] complex, TRUE frequency order.
__global__ __launch_bounds__(256, 4)
void k_rowfft(const float* __restrict__ gen, const float* __restrict__ tgt,
              float2* ws, int img0){
  float2* w = ws ? ws : g_wsfall;
  const int wg   = blockIdx.x;
  const int imgl = wg >> 6;
  const int rg   = wg & 63;
  const int img  = img0 + imgl;
  const int wave = threadIdx.x >> 6, t = threadIdx.x & 63;
  const int pr   = rg*4 + wave;                  // pair index 0..255
  const float* src = (img < 32) ? gen : tgt;
  // float4 view: pair pr starts at float 1024*pr = float4 256*pr.
  const float4* f4 = (const float4*)(src + (size_t)(img & 31) * 786432) + (size_t)pr * 256 + t;

  __shared__ float re_all[4][576], im_all[4][576];
  float* re = re_all[wave];
  float* im = im_all[wave];

  // 12 coalesced float4 loads: rows A (=2pr) and B (=2pr+1), channels R,G,Bl.
  float4 aR0 = f4[0],          aR1 = f4[64];
  float4 bR0 = f4[128],        bR1 = f4[192];
  float4 aG0 = f4[65536],      aG1 = f4[65536+64];
  float4 bG0 = f4[65536+128],  bG1 = f4[65536+192];
  float4 aB0 = f4[131072],     aB1 = f4[131072+64];
  float4 bB0 = f4[131072+128], bB1 = f4[131072+192];

  // Stage gray into LDS at natural x positions (re = rowA, im = rowB).
  const int x0 = 4*t, x1 = 256 + 4*t;
  re[padi(x0+0)] = GRAY1(aR0.x, aG0.x, aB0.x);
  re[padi(x0+1)] = GRAY1(aR0.y, aG0.y, aB0.y);
  re[padi(x0+2)] = GRAY1(aR0.z, aG0.z, aB0.z);
  re[padi(x0+3)] = GRAY1(aR0.w, aG0.w, aB0.w);
  re[padi(x1+0)] = GRAY1(aR1.x, aG1.x, aB1.x);
  re[padi(x1+1)] = GRAY1(aR1.y, aG1.y, aB1.y);
  re[padi(x1+2)] = GRAY1(aR1.z, aG1.z, aB1.z);
  re[padi(x1+3)] = GRAY1(aR1.w, aG1.w, aB1.w);
  im[padi(x0+0)] = GRAY1(bR0.x, bG0.x, bB0.x);
  im[padi(x0+1)] = GRAY1(bR0.y, bG0.y, bB0.y);
  im[padi(x0+2)] = GRAY1(bR0.z, bG0.z, bB0.z);
  im[padi(x0+3)] = GRAY1(bR0.w, bG0.w, bB0.w);
  im[padi(x1+0)] = GRAY1(bR1.x, bG1.x, bB1.x);
  im[padi(x1+1)] = GRAY1(bR1.y, bG1.y, bB1.y);
  im[padi(x1+2)] = GRAY1(bR1.z, bG1.z, bB1.z);
  im[padi(x1+3)] = GRAY1(bR1.w, bG1.w, bB1.w);
  lds_fence();

  // Redistribute: lane t takes x = t + 64j  (z = grayA + i*grayB).
  float2 v[8];
  #pragma unroll
  for (int j = 0; j < 8; ++j){
    const int a = padi(t + 64*j);
    v[j].x = re[a];
    v[j].y = im[a];
  }
  fft512(v, re, im, t);

  // Store in TRUE frequency order: reg j -> kx = 64j + 8(t&7) + (t>>3).
  float2* dst = w + ((size_t)imgl * 256 + pr) * 512;
  const int off = 8*(t & 7) + (t >> 3);
  #pragma unroll
  for (int j = 0; j < 8; ++j) dst[64*j + off] = v[j];   // aligned 512B/instr
}

// Stage 2: column FFTs for kx = 0..256 + masked log10 reduction.
// Blocks 0..31: kx = 8g..8g+7 (2 cols/wave). Block 32: kx=256 (wave 0 only).
// Grid = nimg * 33.
__global__ __launch_bounds__(256)
void k_colfft(const float2* __restrict__ ws, int img0){
  const float2* w = ws ? ws : (const float2*)g_wsfall;
  const int wg   = blockIdx.x;
  const int imgl = wg / 33;
  const int blk  = wg - imgl * 33;
  const int img  = img0 + imgl;
  const int kx0  = blk * 8;
  const int tid  = threadIdx.x;
  const int wave = tid >> 6, t = tid & 63;
  const int ncols = (blk == 32) ? 1 : 8;

  __shared__ float2 own[8][260], mir[8][260];
  __shared__ float re_all[4][576], im_all[4][576];
  float* re = re_all[wave];
  float* im = im_all[wave];

  const float2* zb = w + (size_t)imgl * 131072;     // 256 pairs * 512
  #pragma unroll
  for (int it = 0; it < 8; ++it){
    const int idx = it*256 + tid;                   // 0..2047
    const int p = idx >> 3, e = idx & 7;
    own[e][p] = zb[p*512 + kx0 + e];
    mir[e][p] = zb[p*512 + ((512 - (kx0 + e)) & 511)];
  }
  __syncthreads();

  double acc = 0.0;
  for (int ci = 0; ci < 2; ++ci){
    const int e = wave*2 + ci;
    if (e < ncols){
      const int kx = kx0 + e;
      const bool sub_own = (kx <= 63);              // lowband(kx), kx in 0..256
      const bool sub_mir = (kx >= 1) & (kx <= 64);  // lowband(512-kx)
      const float base = (kx == 0 || kx == 256) ? 1.0f : 2.0f;

      float2 v[8];
      const int u = t >> 1;
      const bool odd = (t & 1);
      #pragma unroll
      for (int j = 0; j < 8; ++j){
        const int p = u + 32*j;
        float2 A = own[e][p];
        float2 B = mir[e][p]; B.y = -B.y;           // conj
        float2 Fe = make_float2((A.x + B.x)*0.5f, (A.y + B.y)*0.5f);
        float2 Fo = mul_mi(make_float2((A.x - B.x)*0.5f, (A.y - B.y)*0.5f));
        v[j] = odd ? Fo : Fe;
      }
      fft512(v, re, im, t);

      #pragma unroll
      for (int j = 0; j < 8; ++j){
        const bool inS  = (j == 0) | (j == 7);
        const bool inSp = (j == 0) | ((j == 1) & (t == 0)) | ((j == 7) & (t != 0));
        float wgt = base;
        if (sub_own & inS)  wgt -= 1.0f;
        if (sub_mir & inSp) wgt -= 1.0f;
        float m2 = fmaf(v[j].x, v[j].x, fmaf(v[j].y, v[j].y, 1e-10f));
        acc += (double)wgt * (double)log10f(m2);
      }
    }
  }
  #pragma unroll
  for (int off = 32; off; off >>= 1) acc += __shfl_down(acc, off);
  if (t == 0) g_partials[((size_t)img * 33 + blk) * 4 + wave] = acc;
}

// Final: psd per image, L1 over batch.
__global__ __launch_bounds__(256)
void k_finish(float* __restrict__ out){
  const int tid = threadIdx.x;
  const int img = tid >> 2, part = tid & 3;
  const double* p = g_partials + (size_t)img * 132 + part;
  double s = 0.0;
  for (int k = 0; k < 33; ++k) s += p[4*k];
  __shared__ double sm[256];
  sm[tid] = s;
  __syncthreads();
  if ((tid & 3) == 0){
    double tot = sm[tid] + sm[tid+1] + sm[tid+2] + sm[tid+3];
    sm[tid] = tot * (1.0 / 245760.0);          // psd[img]
  }
  __syncthreads();
  if (tid < 64){
    double dv = (tid < 32) ? fabs(sm[tid*4] - sm[(tid+32)*4]) : 0.0;
    #pragma unroll
    for (int off = 32; off; off >>= 1) dv += __shfl_down(dv, off);
    if (tid == 0) out[0] = (float)(dv * (1.0 / 32.0));
  }
}

extern "C" void kernel_launch(void* const* d_in, const int* in_sizes, int n_in,
                              void* d_out, int out_size, void* d_ws, size_t ws_size,
                              hipStream_t stream){
  (void)in_sizes; (void)n_in; (void)out_size;
  const float* gen = (const float*)d_in[0];
  const float* tgt = (const float*)d_in[1];
  float* out = (float*)d_out;

  const size_t per_img = (size_t)256 * 512 * sizeof(float2);   // 1 MiB
  int chunk = (int)(ws_size / per_img);
  float2* wsp = (float2*)d_ws;
  if (chunk < 1){ chunk = 1; wsp = nullptr; }   // static 1-image fallback
  if (chunk > 64) chunk = 64;

  for (int i0 = 0; i0 < 64; i0 += chunk){
    const int n = (64 - i0 < chunk) ? (64 - i0) : chunk;
    k_rowfft<<<dim3(n * 64), dim3(256), 0, stream>>>(gen, tgt, wsp, i0);
    k_colfft<<<dim3(n * 33), dim3(256), 0, stream>>>(wsp, i0);
  }
  k_finish<<<dim3(1), dim3(256), 0, stream>>>(out);
}

// Round 5
// 76.136 us; speedup vs baseline: 1.5701x; 1.0012x over previous
//
#include <hip/hip_runtime.h>
#include <hip/hip_bf16.h>
#include <math.h>

// ---------------------------------------------------------------------------
// HighFreqSuppressionLoss, real-packed rows + Hermitian-halved columns.
// gray = (0.299R+0.587G+0.114B+1)/2; F = fft2(gray);
// loss = mean_b | mean_M log10(|F_gen|^2+eps) - mean_M log10(|F_tgt|^2+eps) |
// Mask excludes (kx,ky) iff lowband(kx)&&lowband(ky); lowband: k<64||k>=448.
//
// Stage 1: pack rows (2p,2p+1) as z = a+ib, one 512-pt FFT per pair, store in
//   TRUE FREQUENCY ORDER: ws[img][pair p][kx], kx = 64j + 8(t&7) + (t>>3).
//   DUAL-FFT per wave: each wave runs two pairs' FFTs with interleaved phases
//   (ILP during LDS/mem latency; one fence per phase covers both).
// Stage 2 (kx = 0..256 only; Hermitian PSD symmetry covers the rest):
//   A_p = Z_p[kx], B_p = conj(Z_p[(512-kx)&511]);
//   f[2p] = (A+B)/2, f[2p+1] = -i(A-B)/2;  column FFT over y of f.
//   Element weight: base = (kx==0||kx==256)?1:2, minus [kx<=63]*[ky in S],
//   minus [1<=kx<=64]*[ky in S'];  S <=> j==0||j==7,
//   S' <=> j==0 || (j==1&&t==0) || (j==7&&t!=0).  (weights total 245760)
// ---------------------------------------------------------------------------

__device__ double g_partials[64 * 33 * 4];              // [img][blk][wave]
__device__ __align__(16) float2 g_wsfall[256 * 512];    // 1-image fallback

__device__ __forceinline__ float2 cadd(float2 a, float2 b){ return make_float2(a.x+b.x, a.y+b.y); }
__device__ __forceinline__ float2 csub(float2 a, float2 b){ return make_float2(a.x-b.x, a.y-b.y); }
__device__ __forceinline__ float2 cmul(float2 a, float2 b){
  return make_float2(fmaf(a.x, b.x, -(a.y*b.y)), fmaf(a.x, b.y, a.y*b.x));
}
__device__ __forceinline__ float2 mul_mi(float2 a){ return make_float2(a.y, -a.x); } // *(-i)

__device__ __forceinline__ void fft8(float2 v[8]){
  const float S = 0.70710678118654752440f;
  float2 c0=cadd(v[0],v[4]), c1=cadd(v[1],v[5]), c2=cadd(v[2],v[6]), c3=cadd(v[3],v[7]);
  float2 d0=csub(v[0],v[4]);
  float2 t1=csub(v[1],v[5]);
  float2 d1=make_float2(S*(t1.x+t1.y), S*(t1.y-t1.x));   // *w8^1
  float2 d2=mul_mi(csub(v[2],v[6]));                     // *w8^2
  float2 t3=csub(v[3],v[7]);
  float2 d3=make_float2(S*(t3.y-t3.x), -S*(t3.x+t3.y));  // *w8^3
  float2 e0=cadd(c0,c2), e1=cadd(c1,c3), f0=csub(c0,c2), f1=mul_mi(csub(c1,c3));
  float2 g0=cadd(d0,d2), g1=cadd(d1,d3), h0=csub(d0,d2), h1=mul_mi(csub(d1,d3));
  v[0]=cadd(e0,e1); v[4]=csub(e0,e1);
  v[2]=cadd(f0,f1); v[6]=csub(f0,f1);
  v[1]=cadd(g0,g1); v[5]=csub(g0,g1);
  v[3]=cadd(h0,h1); v[7]=csub(h0,h1);
}

__device__ __forceinline__ void twiddle8w(float2 v[8], float2 w){
  float2 wp = w;
  v[1] = cmul(v[1], wp);
  #pragma unroll
  for (int m = 2; m < 8; ++m){ wp = cmul(wp, w); v[m] = cmul(v[m], wp); }
}

__device__ __forceinline__ int padi(int i){ return i + (i >> 3); }

// Wave-internal LDS fence (exchange is intra-wave; no block barrier needed).
__device__ __forceinline__ void lds_fence(){
  asm volatile("s_waitcnt lgkmcnt(0)" ::: "memory");
  __builtin_amdgcn_sched_barrier(0);
}

// Two interleaved 512-pt DIF FFTs across one wave. Lane t holds x[t+64j].
// Exit: reg j of lane t = stored s = 8t+j, true freq 64j + 8(t&7) + (t>>3).
__device__ __forceinline__ void fft512x2(float2 va[8], float2 vb[8],
                                         float* rea, float* ima,
                                         float* reb, float* imb, int t){
  const float TW = -6.28318530717958647692f;
  float sn, cs;
  fft8(va); fft8(vb);
  __sincosf(TW * (float)t * (1.0f/512.0f), &sn, &cs);
  { float2 w = make_float2(cs, sn); twiddle8w(va, w); twiddle8w(vb, w); }
  lds_fence();
  #pragma unroll
  for (int m = 0; m < 8; ++m){
    int a = padi(m*64 + t);
    rea[a] = va[m].x; ima[a] = va[m].y;
    reb[a] = vb[m].x; imb[a] = vb[m].y;
  }
  lds_fence();
  const int q = t >> 3, n = t & 7;
  #pragma unroll
  for (int j = 0; j < 8; ++j){
    int a = padi(q*64 + n + 8*j);
    va[j].x = rea[a]; va[j].y = ima[a];
    vb[j].x = reb[a]; vb[j].y = imb[a];
  }
  fft8(va); fft8(vb);
  __sincosf(TW * (float)n * (1.0f/64.0f), &sn, &cs);
  { float2 w = make_float2(cs, sn); twiddle8w(va, w); twiddle8w(vb, w); }
  lds_fence();
  #pragma unroll
  for (int m = 0; m < 8; ++m){
    int a = padi(q*64 + m*8 + n);
    rea[a] = va[m].x; ima[a] = va[m].y;
    reb[a] = vb[m].x; imb[a] = vb[m].y;
  }
  lds_fence();
  #pragma unroll
  for (int j = 0; j < 8; ++j){
    int a = padi(q*64 + n*8 + j);
    va[j].x = rea[a]; va[j].y = ima[a];
    vb[j].x = reb[a]; vb[j].y = imb[a];
  }
  fft8(va); fft8(vb);
}

#define GRAY1(r,g,b) ((fmaf(0.299f,(r), fmaf(0.587f,(g), 0.114f*(b))) + 1.0f)*0.5f)
__device__ __forceinline__ float4 gray4(float4 r, float4 g, float4 b){
  return make_float4(GRAY1(r.x,g.x,b.x), GRAY1(r.y,g.y,b.y),
                     GRAY1(r.z,g.z,b.z), GRAY1(r.w,g.w,b.w));
}

// Stage 1: packed row-pair FFTs, 2 pairs per wave. Block 256 = 4 waves.
// Grid = nimg * 32.  ws: [img_local][pair][kx] complex, TRUE frequency order.
__global__ __launch_bounds__(256, 2)
void k_rowfft(const float* __restrict__ gen, const float* __restrict__ tgt,
              float2* ws, int img0){
  float2* w = ws ? ws : g_wsfall;
  const int wg   = blockIdx.x;
  const int imgl = wg >> 5;
  const int rg   = wg & 31;
  const int img  = img0 + imgl;
  const int wave = threadIdx.x >> 6, t = threadIdx.x & 63;
  const int prA  = rg*8 + wave*2;                // pair indices (adjacent)
  const int prB  = prA + 1;
  const float* src = (img < 32) ? gen : tgt;
  const float4* f4 = (const float4*)(src + (size_t)(img & 31) * 786432);
  const float4* fA = f4 + (size_t)prA * 256 + t;
  const float4* fB = f4 + (size_t)prB * 256 + t;

  __shared__ float ex[4][4][576];                // [wave][reA,imA,reB,imB]
  float* reA = ex[wave][0]; float* imA = ex[wave][1];
  float* reB = ex[wave][2]; float* imB = ex[wave][3];

  // 24 coalesced float4 loads (1KB/instr), all in flight together.
  float4 ArR0 = fA[0],             ArR1 = fA[64];
  float4 AsR0 = fA[128],           AsR1 = fA[192];
  float4 ArG0 = fA[65536],         ArG1 = fA[65536+64];
  float4 AsG0 = fA[65536+128],     AsG1 = fA[65536+192];
  float4 ArB0 = fA[131072],        ArB1 = fA[131072+64];
  float4 AsB0 = fA[131072+128],    AsB1 = fA[131072+192];
  float4 BrR0 = fB[0],             BrR1 = fB[64];
  float4 BsR0 = fB[128],           BsR1 = fB[192];
  float4 BrG0 = fB[65536],         BrG1 = fB[65536+64];
  float4 BsG0 = fB[65536+128],     BsG1 = fB[65536+192];
  float4 BrB0 = fB[131072],        BrB1 = fB[131072+64];
  float4 BsB0 = fB[131072+128],    BsB1 = fB[131072+192];

  // Stage gray via b128 LDS writes into unpadded natural layout
  // (banks: b128 x 64 lanes = 8-way = optimal; natural b32 reads are 2-way).
  ((float4*)reA)[t]      = gray4(ArR0, ArG0, ArB0);
  ((float4*)reA)[64 + t] = gray4(ArR1, ArG1, ArB1);
  ((float4*)imA)[t]      = gray4(AsR0, AsG0, AsB0);
  ((float4*)imA)[64 + t] = gray4(AsR1, AsG1, AsB1);
  ((float4*)reB)[t]      = gray4(BrR0, BrG0, BrB0);
  ((float4*)reB)[64 + t] = gray4(BrR1, BrG1, BrB1);
  ((float4*)imB)[t]      = gray4(BsR0, BsG0, BsB0);
  ((float4*)imB)[64 + t] = gray4(BsR1, BsG1, BsB1);
  lds_fence();

  float2 va[8], vb[8];
  #pragma unroll
  for (int j = 0; j < 8; ++j){
    va[j] = make_float2(reA[t + 64*j], imA[t + 64*j]);
    vb[j] = make_float2(reB[t + 64*j], imB[t + 64*j]);
  }
  fft512x2(va, vb, reA, imA, reB, imB, t);

  // Store in TRUE frequency order: reg j -> kx = 64j + 8(t&7) + (t>>3).
  float2* dstA = w + ((size_t)imgl * 256 + prA) * 512;
  float2* dstB = w + ((size_t)imgl * 256 + prB) * 512;
  const int off = 8*(t & 7) + (t >> 3);
  #pragma unroll
  for (int j = 0; j < 8; ++j){
    dstA[64*j + off] = va[j];                    // aligned 512B/instr
    dstB[64*j + off] = vb[j];
  }
}

// Stage 2: column FFTs for kx = 0..256 + masked log10 reduction.
// Blocks 0..31: kx = 8g..8g+7 (2 cols/wave). Block 32: kx=256 (wave 0 only).
// Grid = nimg * 33.
__global__ __launch_bounds__(256)
void k_colfft(const float2* __restrict__ ws, int img0){
  const float2* w = ws ? ws : (const float2*)g_wsfall;
  const int wg   = blockIdx.x;
  const int imgl = wg / 33;
  const int blk  = wg - imgl * 33;
  const int img  = img0 + imgl;
  const int kx0  = blk * 8;
  const int tid  = threadIdx.x;
  const int wave = tid >> 6, t = tid & 63;
  const int ncols = (blk == 32) ? 1 : 8;

  __shared__ float2 own[8][260], mir[8][260];
  __shared__ float re_all[4][576], im_all[4][576];
  float* re = re_all[wave];
  float* im = im_all[wave];

  const float2* zb = w + (size_t)imgl * 131072;     // 256 pairs * 512
  #pragma unroll
  for (int it = 0; it < 8; ++it){
    const int idx = it*256 + tid;                   // 0..2047
    const int p = idx >> 3, e = idx & 7;
    own[e][p] = zb[p*512 + kx0 + e];
    mir[e][p] = zb[p*512 + ((512 - (kx0 + e)) & 511)];
  }
  __syncthreads();

  const float TW = -6.28318530717958647692f;
  double acc = 0.0;
  for (int ci = 0; ci < 2; ++ci){
    const int e = wave*2 + ci;
    if (e < ncols){
      const int kx = kx0 + e;
      const bool sub_own = (kx <= 63);              // lowband(kx), kx in 0..256
      const bool sub_mir = (kx >= 1) & (kx <= 64);  // lowband(512-kx)
      const float base = (kx == 0 || kx == 256) ? 1.0f : 2.0f;

      float2 v[8];
      const int u = t >> 1;
      const bool odd = (t & 1);
      #pragma unroll
      for (int j = 0; j < 8; ++j){
        const int p = u + 32*j;
        float2 A = own[e][p];
        float2 B = mir[e][p]; B.y = -B.y;           // conj
        float2 Fe = make_float2((A.x + B.x)*0.5f, (A.y + B.y)*0.5f);
        float2 Fo = mul_mi(make_float2((A.x - B.x)*0.5f, (A.y - B.y)*0.5f));
        v[j] = odd ? Fo : Fe;
      }
      // single-stream fft512 (reuse dual core with dummy second stream would
      // waste LDS; keep original phases inline)
      {
        float sn, cs;
        fft8(v);
        __sincosf(TW * (float)t * (1.0f/512.0f), &sn, &cs);
        { float2 wtw = make_float2(cs, sn); twiddle8w(v, wtw); }
        lds_fence();
        #pragma unroll
        for (int m = 0; m < 8; ++m){ int a = padi(m*64 + t); re[a] = v[m].x; im[a] = v[m].y; }
        lds_fence();
        const int q = t >> 3, n = t & 7;
        #pragma unroll
        for (int j = 0; j < 8; ++j){ int a = padi(q*64 + n + 8*j); v[j].x = re[a]; v[j].y = im[a]; }
        fft8(v);
        __sincosf(TW * (float)n * (1.0f/64.0f), &sn, &cs);
        { float2 wtw = make_float2(cs, sn); twiddle8w(v, wtw); }
        lds_fence();
        #pragma unroll
        for (int m = 0; m < 8; ++m){ int a = padi(q*64 + m*8 + n); re[a] = v[m].x; im[a] = v[m].y; }
        lds_fence();
        #pragma unroll
        for (int j = 0; j < 8; ++j){ int a = padi(q*64 + n*8 + j); v[j].x = re[a]; v[j].y = im[a]; }
        fft8(v);
      }

      #pragma unroll
      for (int j = 0; j < 8; ++j){
        const bool inS  = (j == 0) | (j == 7);
        const bool inSp = (j == 0) | ((j == 1) & (t == 0)) | ((j == 7) & (t != 0));
        float wgt = base;
        if (sub_own & inS)  wgt -= 1.0f;
        if (sub_mir & inSp) wgt -= 1.0f;
        float m2 = fmaf(v[j].x, v[j].x, fmaf(v[j].y, v[j].y, 1e-10f));
        acc += (double)wgt * (double)log10f(m2);
      }
    }
  }
  #pragma unroll
  for (int off = 32; off; off >>= 1) acc += __shfl_down(acc, off);
  if (t == 0) g_partials[((size_t)img * 33 + blk) * 4 + wave] = acc;
}

// Final: psd per image, L1 over batch.
__global__ __launch_bounds__(256)
void k_finish(float* __restrict__ out){
  const int tid = threadIdx.x;
  const int img = tid >> 2, part = tid & 3;
  const double* p = g_partials + (size_t)img * 132 + part;
  double s = 0.0;
  for (int k = 0; k < 33; ++k) s += p[4*k];
  __shared__ double sm[256];
  sm[tid] = s;
  __syncthreads();
  if ((tid & 3) == 0){
    double tot = sm[tid] + sm[tid+1] + sm[tid+2] + sm[tid+3];
    sm[tid] = tot * (1.0 / 245760.0);          // psd[img]
  }
  __syncthreads();
  if (tid < 64){
    double dv = (tid < 32) ? fabs(sm[tid*4] - sm[(tid+32)*4]) : 0.0;
    #pragma unroll
    for (int off = 32; off; off >>= 1) dv += __shfl_down(dv, off);
    if (tid == 0) out[0] = (float)(dv * (1.0 / 32.0));
  }
}

extern "C" void kernel_launch(void* const* d_in, const int* in_sizes, int n_in,
                              void* d_out, int out_size, void* d_ws, size_t ws_size,
                              hipStream_t stream){
  (void)in_sizes; (void)n_in; (void)out_size;
  const float* gen = (const float*)d_in[0];
  const float* tgt = (const float*)d_in[1];
  float* out = (float*)d_out;

  const size_t per_img = (size_t)256 * 512 * sizeof(float2);   // 1 MiB
  int chunk = (int)(ws_size / per_img);
  float2* wsp = (float2*)d_ws;
  if (chunk < 1){ chunk = 1; wsp = nullptr; }   // static 1-image fallback
  if (chunk > 64) chunk = 64;

  for (int i0 = 0; i0 < 64; i0 += chunk){
    const int n = (64 - i0 < chunk) ? (64 - i0) : chunk;
    k_rowfft<<<dim3(n * 32), dim3(256), 0, stream>>>(gen, tgt, wsp, i0);
    k_colfft<<<dim3(n * 33), dim3(256), 0, stream>>>(wsp, i0);
  }
  k_finish<<<dim3(1), dim3(256), 0, stream>>>(out);
}

// Round 6
// 74.794 us; speedup vs baseline: 1.5982x; 1.0179x over previous
//
#include <hip/hip_runtime.h>
#include <hip/hip_bf16.h>
#include <math.h>

// ---------------------------------------------------------------------------
// HighFreqSuppressionLoss, real-packed rows + Hermitian-halved columns.
// gray = (0.299R+0.587G+0.114B+1)/2; F = fft2(gray);
// loss = mean_b | mean_M log10(|F_gen|^2+eps) - mean_M log10(|F_tgt|^2+eps) |
// Mask excludes (kx,ky) iff lowband(kx)&&lowband(ky); lowband: k<64||k>=448.
//
// Stage 1: pack rows (2p,2p+1) as z = a+ib, one 512-pt FFT per pair, store in
//   TRUE FREQUENCY ORDER: ws[img][pair p][kx], kx = 64j + 8(t&7) + (t>>3).
//   Input staged HBM->LDS via global_load_lds (12 x 1KB DMA per wave, zero
//   VGPR payload, all in flight together); staging buffer reused as the FFT
//   exchange buffer after the gray values are consumed into registers.
// Stage 2 (kx = 0..256 only; Hermitian PSD symmetry covers the rest):
//   A_p = Z_p[kx], B_p = conj(Z_p[(512-kx)&511]);
//   f[2p] = (A+B)/2, f[2p+1] = -i(A-B)/2;  column FFT over y of f.
//   Element weight: base = (kx==0||kx==256)?1:2, minus [kx<=63]*[ky in S],
//   minus [1<=kx<=64]*[ky in S'];  S <=> j==0||j==7,
//   S' <=> j==0 || (j==1&&t==0) || (j==7&&t!=0).  (weights total 245760)
// ---------------------------------------------------------------------------

__device__ double g_partials[64 * 33 * 4];              // [img][blk][wave]
__device__ __align__(16) float2 g_wsfall[256 * 512];    // 1-image fallback

__device__ __forceinline__ float2 cadd(float2 a, float2 b){ return make_float2(a.x+b.x, a.y+b.y); }
__device__ __forceinline__ float2 csub(float2 a, float2 b){ return make_float2(a.x-b.x, a.y-b.y); }
__device__ __forceinline__ float2 cmul(float2 a, float2 b){
  return make_float2(fmaf(a.x, b.x, -(a.y*b.y)), fmaf(a.x, b.y, a.y*b.x));
}
__device__ __forceinline__ float2 mul_mi(float2 a){ return make_float2(a.y, -a.x); } // *(-i)

__device__ __forceinline__ void fft8(float2 v[8]){
  const float S = 0.70710678118654752440f;
  float2 c0=cadd(v[0],v[4]), c1=cadd(v[1],v[5]), c2=cadd(v[2],v[6]), c3=cadd(v[3],v[7]);
  float2 d0=csub(v[0],v[4]);
  float2 t1=csub(v[1],v[5]);
  float2 d1=make_float2(S*(t1.x+t1.y), S*(t1.y-t1.x));   // *w8^1
  float2 d2=mul_mi(csub(v[2],v[6]));                     // *w8^2
  float2 t3=csub(v[3],v[7]);
  float2 d3=make_float2(S*(t3.y-t3.x), -S*(t3.x+t3.y));  // *w8^3
  float2 e0=cadd(c0,c2), e1=cadd(c1,c3), f0=csub(c0,c2), f1=mul_mi(csub(c1,c3));
  float2 g0=cadd(d0,d2), g1=cadd(d1,d3), h0=csub(d0,d2), h1=mul_mi(csub(d1,d3));
  v[0]=cadd(e0,e1); v[4]=csub(e0,e1);
  v[2]=cadd(f0,f1); v[6]=csub(f0,f1);
  v[1]=cadd(g0,g1); v[5]=csub(g0,g1);
  v[3]=cadd(h0,h1); v[7]=csub(h0,h1);
}

__device__ __forceinline__ void twiddle8(float2 v[8], float ang){
  float sn, cs;
  __sincosf(ang, &sn, &cs);
  float2 w = make_float2(cs, sn);
  float2 wp = w;
  v[1] = cmul(v[1], wp);
  #pragma unroll
  for (int m = 2; m < 8; ++m){ wp = cmul(wp, w); v[m] = cmul(v[m], wp); }
}

__device__ __forceinline__ int padi(int i){ return i + (i >> 3); }

// Wave-internal LDS fence (exchange is intra-wave; no block barrier needed).
__device__ __forceinline__ void lds_fence(){
  asm volatile("s_waitcnt lgkmcnt(0)" ::: "memory");
  __builtin_amdgcn_sched_barrier(0);
}

// 512-pt DIF FFT across one wave. Lane t holds x[t+64j] on entry.
// Exit: reg j of lane t = stored s = 8t+j, true freq 64j + 8(t&7) + (t>>3).
__device__ __forceinline__ void fft512(float2 v[8], float* re, float* im, int t){
  const float TW = -6.28318530717958647692f;
  fft8(v);
  twiddle8(v, TW * (float)t * (1.0f/512.0f));
  lds_fence();
  #pragma unroll
  for (int m = 0; m < 8; ++m){ int a = padi(m*64 + t); re[a] = v[m].x; im[a] = v[m].y; }
  lds_fence();
  const int q = t >> 3, n = t & 7;
  #pragma unroll
  for (int j = 0; j < 8; ++j){ int a = padi(q*64 + n + 8*j); v[j].x = re[a]; v[j].y = im[a]; }
  fft8(v);
  twiddle8(v, TW * (float)n * (1.0f/64.0f));
  lds_fence();
  #pragma unroll
  for (int m = 0; m < 8; ++m){ int a = padi(q*64 + m*8 + n); re[a] = v[m].x; im[a] = v[m].y; }
  lds_fence();
  #pragma unroll
  for (int j = 0; j < 8; ++j){ int a = padi(q*64 + n*8 + j); v[j].x = re[a]; v[j].y = im[a]; }
  fft8(v);
}

#define GRAY1(r,g,b) ((fmaf(0.299f,(r), fmaf(0.587f,(g), 0.114f*(b))) + 1.0f)*0.5f)

// Stage 1: packed row-pair FFTs, 1 pair/wave, input via global_load_lds DMA.
// Block 256 = 4 waves. Grid = nimg * 64.
// ws: [img_local][pair][kx] complex, TRUE frequency order.
__global__ __launch_bounds__(256, 3)
void k_rowfft(const float* __restrict__ gen, const float* __restrict__ tgt,
              float2* ws, int img0){
  float2* w = ws ? ws : g_wsfall;
  const int wg   = blockIdx.x;
  const int imgl = wg >> 6;
  const int rg   = wg & 63;
  const int img  = img0 + imgl;
  const int wave = threadIdx.x >> 6, t = threadIdx.x & 63;
  const int pr   = rg*4 + wave;                  // pair index 0..255
  const float* src = (img < 32) ? gen : tgt;
  // rows 2pr,2pr+1 are contiguous 1024 floats within each channel plane
  const float* base = src + (size_t)(img & 31) * 786432 + (size_t)pr * 1024;

  // Per-wave 12KB staging: [ch][rowA(512) rowB(512)]; reused as exchange.
  __shared__ float stage_all[4][3072];
  float* st = stage_all[wave];

  // 12 direct-to-LDS DMA loads, 1KB each (64 lanes x 16B), zero VGPR payload.
  // Source per-lane: base + ch*262144 + seg*256 + 4t (16B aligned).
  // Dest wave-uniform: st + ch*1024 + seg*256 (+ lane*16B by HW).
  #pragma unroll
  for (int ch = 0; ch < 3; ++ch){
    const float* pb = base + ch * 262144 + 4*t;
    float* lb = st + ch*1024;
    #pragma unroll
    for (int seg = 0; seg < 4; ++seg){
      __builtin_amdgcn_global_load_lds(
        (const __attribute__((address_space(1))) void*)(pb + seg*256),
        (__attribute__((address_space(3))) void*)(lb + seg*256),
        16, 0, 0);
    }
  }
  asm volatile("s_waitcnt vmcnt(0)" ::: "memory");
  __builtin_amdgcn_sched_barrier(0);

  // Gray from LDS: stride-1 across lanes -> conflict-free b32 reads.
  float2 v[8];
  #pragma unroll
  for (int j = 0; j < 8; ++j){
    const int x = t + 64*j;
    float rA = st[x],        rB = st[512 + x];
    float gA = st[1024 + x], gB = st[1536 + x];
    float bA = st[2048 + x], bB = st[2560 + x];
    v[j] = make_float2(GRAY1(rA, gA, bA), GRAY1(rB, gB, bB));
  }
  // Exchange reuses staging: re=[0,576), im=[1024,1600). All staging reads
  // are drained by fft512's lds_fence before its first exchange write.
  fft512(v, st, st + 1024, t);

  // Store in TRUE frequency order: reg j -> kx = 64j + 8(t&7) + (t>>3).
  float2* dst = w + ((size_t)imgl * 256 + pr) * 512;
  const int off = 8*(t & 7) + (t >> 3);
  #pragma unroll
  for (int j = 0; j < 8; ++j) dst[64*j + off] = v[j];   // aligned 512B/instr
}

// Stage 2: column FFTs for kx = 0..256 + masked log10 reduction.
// Blocks 0..31: kx = 8g..8g+7 (2 cols/wave). Block 32: kx=256 (wave 0 only).
// Grid = nimg * 33.
__global__ __launch_bounds__(256)
void k_colfft(const float2* __restrict__ ws, int img0){
  const float2* w = ws ? ws : (const float2*)g_wsfall;
  const int wg   = blockIdx.x;
  const int imgl = wg / 33;
  const int blk  = wg - imgl * 33;
  const int img  = img0 + imgl;
  const int kx0  = blk * 8;
  const int tid  = threadIdx.x;
  const int wave = tid >> 6, t = tid & 63;
  const int ncols = (blk == 32) ? 1 : 8;

  __shared__ float2 own[8][260], mir[8][260];
  __shared__ float re_all[4][576], im_all[4][576];
  float* re = re_all[wave];
  float* im = im_all[wave];

  const float2* zb = w + (size_t)imgl * 131072;     // 256 pairs * 512
  #pragma unroll
  for (int it = 0; it < 8; ++it){
    const int idx = it*256 + tid;                   // 0..2047
    const int p = idx >> 3, e = idx & 7;
    own[e][p] = zb[p*512 + kx0 + e];
    mir[e][p] = zb[p*512 + ((512 - (kx0 + e)) & 511)];
  }
  __syncthreads();

  double acc = 0.0;
  for (int ci = 0; ci < 2; ++ci){
    const int e = wave*2 + ci;
    if (e < ncols){
      const int kx = kx0 + e;
      const bool sub_own = (kx <= 63);              // lowband(kx), kx in 0..256
      const bool sub_mir = (kx >= 1) & (kx <= 64);  // lowband(512-kx)
      const float base = (kx == 0 || kx == 256) ? 1.0f : 2.0f;

      float2 v[8];
      const int u = t >> 1;
      const bool odd = (t & 1);
      #pragma unroll
      for (int j = 0; j < 8; ++j){
        const int p = u + 32*j;
        float2 A = own[e][p];
        float2 B = mir[e][p]; B.y = -B.y;           // conj
        float2 Fe = make_float2((A.x + B.x)*0.5f, (A.y + B.y)*0.5f);
        float2 Fo = mul_mi(make_float2((A.x - B.x)*0.5f, (A.y - B.y)*0.5f));
        v[j] = odd ? Fo : Fe;
      }
      fft512(v, re, im, t);

      #pragma unroll
      for (int j = 0; j < 8; ++j){
        const bool inS  = (j == 0) | (j == 7);
        const bool inSp = (j == 0) | ((j == 1) & (t == 0)) | ((j == 7) & (t != 0));
        float wgt = base;
        if (sub_own & inS)  wgt -= 1.0f;
        if (sub_mir & inSp) wgt -= 1.0f;
        float m2 = fmaf(v[j].x, v[j].x, fmaf(v[j].y, v[j].y, 1e-10f));
        acc += (double)wgt * (double)log10f(m2);
      }
    }
  }
  #pragma unroll
  for (int off = 32; off; off >>= 1) acc += __shfl_down(acc, off);
  if (t == 0) g_partials[((size_t)img * 33 + blk) * 4 + wave] = acc;
}

// Final: psd per image, L1 over batch.
__global__ __launch_bounds__(256)
void k_finish(float* __restrict__ out){
  const int tid = threadIdx.x;
  const int img = tid >> 2, part = tid & 3;
  const double* p = g_partials + (size_t)img * 132 + part;
  double s = 0.0;
  for (int k = 0; k < 33; ++k) s += p[4*k];
  __shared__ double sm[256];
  sm[tid] = s;
  __syncthreads();
  if ((tid & 3) == 0){
    double tot = sm[tid] + sm[tid+1] + sm[tid+2] + sm[tid+3];
    sm[tid] = tot * (1.0 / 245760.0);          // psd[img]
  }
  __syncthreads();
  if (tid < 64){
    double dv = (tid < 32) ? fabs(sm[tid*4] - sm[(tid+32)*4]) : 0.0;
    #pragma unroll
    for (int off = 32; off; off >>= 1) dv += __shfl_down(dv, off);
    if (tid == 0) out[0] = (float)(dv * (1.0 / 32.0));
  }
}

extern "C" void kernel_launch(void* const* d_in, const int* in_sizes, int n_in,
                              void* d_out, int out_size, void* d_ws, size_t ws_size,
                              hipStream_t stream){
  (void)in_sizes; (void)n_in; (void)out_size;
  const float* gen = (const float*)d_in[0];
  const float* tgt = (const float*)d_in[1];
  float* out = (float*)d_out;

  const size_t per_img = (size_t)256 * 512 * sizeof(float2);   // 1 MiB
  int chunk = (int)(ws_size / per_img);
  float2* wsp = (float2*)d_ws;
  if (chunk < 1){ chunk = 1; wsp = nullptr; }   // static 1-image fallback
  if (chunk > 64) chunk = 64;

  for (int i0 = 0; i0 < 64; i0 += chunk){
    const int n = (64 - i0 < chunk) ? (64 - i0) : chunk;
    k_rowfft<<<dim3(n * 64), dim3(256), 0, stream>>>(gen, tgt, wsp, i0);
    k_colfft<<<dim3(n * 33), dim3(256), 0, stream>>>(wsp, i0);
  }
  k_finish<<<dim3(1), dim3(256), 0, stream>>>(out);
}

// Round 7
// 72.435 us; speedup vs baseline: 1.6503x; 1.0326x over previous
//
#include <hip/hip_runtime.h>
#include <hip/hip_bf16.h>
#include <hip/hip_fp16.h>
#include <math.h>

// ---------------------------------------------------------------------------
// HighFreqSuppressionLoss, real-packed rows + Hermitian-halved columns.
// gray = (0.299R+0.587G+0.114B+1)/2; F = fft2(gray);
// loss = mean_b | mean_M log10(|F_gen|^2+eps) - mean_M log10(|F_tgt|^2+eps) |
// Mask excludes (kx,ky) iff lowband(kx)&&lowband(ky); lowband: k<64||k>=448.
//
// Stage 1 (pipelined): pack rows (2p,2p+1) as z = a+ib, one 512-pt FFT/pair.
//   Each wave processes 8 pairs with double-buffered LDS staging:
//   DMA(n+1) is issued BEFORE FFT(n) computes, waits are counted vmcnt
//   (12/20/8, never draining the prefetch) so ~12KB stays in flight per wave
//   continuously -> streams at the per-CU HBM rate instead of burst+stall.
//   Z stored fp16 (half2) in TRUE FREQUENCY ORDER: ws[img][pair][kx],
//   kx = 64j + 8(t&7) + (t>>3).  (fp16 quantization -> psd err ~5e-7 << tol)
// Stage 2 (kx = 0..256 only; Hermitian PSD symmetry covers the rest):
//   A_p = Z_p[kx], B_p = conj(Z_p[(512-kx)&511]);
//   f[2p] = (A+B)/2, f[2p+1] = -i(A-B)/2;  column FFT over y of f.
//   Element weight: base = (kx==0||kx==256)?1:2, minus [kx<=63]*[ky in S],
//   minus [1<=kx<=64]*[ky in S'];  S <=> j==0||j==7,
//   S' <=> j==0 || (j==1&&t==0) || (j==7&&t!=0).  (weights total 245760)
// ---------------------------------------------------------------------------

__device__ double g_partials[64 * 33 * 4];              // [img][blk][wave]
__device__ __align__(16) __half2 g_wsfall[256 * 512];   // 1-image fallback

__device__ __forceinline__ float2 cadd(float2 a, float2 b){ return make_float2(a.x+b.x, a.y+b.y); }
__device__ __forceinline__ float2 csub(float2 a, float2 b){ return make_float2(a.x-b.x, a.y-b.y); }
__device__ __forceinline__ float2 cmul(float2 a, float2 b){
  return make_float2(fmaf(a.x, b.x, -(a.y*b.y)), fmaf(a.x, b.y, a.y*b.x));
}
__device__ __forceinline__ float2 mul_mi(float2 a){ return make_float2(a.y, -a.x); } // *(-i)

__device__ __forceinline__ void fft8(float2 v[8]){
  const float S = 0.70710678118654752440f;
  float2 c0=cadd(v[0],v[4]), c1=cadd(v[1],v[5]), c2=cadd(v[2],v[6]), c3=cadd(v[3],v[7]);
  float2 d0=csub(v[0],v[4]);
  float2 t1=csub(v[1],v[5]);
  float2 d1=make_float2(S*(t1.x+t1.y), S*(t1.y-t1.x));   // *w8^1
  float2 d2=mul_mi(csub(v[2],v[6]));                     // *w8^2
  float2 t3=csub(v[3],v[7]);
  float2 d3=make_float2(S*(t3.y-t3.x), -S*(t3.x+t3.y));  // *w8^3
  float2 e0=cadd(c0,c2), e1=cadd(c1,c3), f0=csub(c0,c2), f1=mul_mi(csub(c1,c3));
  float2 g0=cadd(d0,d2), g1=cadd(d1,d3), h0=csub(d0,d2), h1=mul_mi(csub(d1,d3));
  v[0]=cadd(e0,e1); v[4]=csub(e0,e1);
  v[2]=cadd(f0,f1); v[6]=csub(f0,f1);
  v[1]=cadd(g0,g1); v[5]=csub(g0,g1);
  v[3]=cadd(h0,h1); v[7]=csub(h0,h1);
}

__device__ __forceinline__ void twiddle8(float2 v[8], float ang){
  float sn, cs;
  __sincosf(ang, &sn, &cs);
  float2 w = make_float2(cs, sn);
  float2 wp = w;
  v[1] = cmul(v[1], wp);
  #pragma unroll
  for (int m = 2; m < 8; ++m){ wp = cmul(wp, w); v[m] = cmul(v[m], wp); }
}

__device__ __forceinline__ int padi(int i){ return i + (i >> 3); }

// Wave-internal LDS fence (exchange is intra-wave; no block barrier needed).
__device__ __forceinline__ void lds_fence(){
  asm volatile("s_waitcnt lgkmcnt(0)" ::: "memory");
  __builtin_amdgcn_sched_barrier(0);
}

// 512-pt DIF FFT across one wave. Lane t holds x[t+64j] on entry.
// Exit: reg j of lane t = stored s = 8t+j, true freq 64j + 8(t&7) + (t>>3).
__device__ __forceinline__ void fft512(float2 v[8], float* re, float* im, int t){
  const float TW = -6.28318530717958647692f;
  fft8(v);
  twiddle8(v, TW * (float)t * (1.0f/512.0f));
  lds_fence();
  #pragma unroll
  for (int m = 0; m < 8; ++m){ int a = padi(m*64 + t); re[a] = v[m].x; im[a] = v[m].y; }
  lds_fence();
  const int q = t >> 3, n = t & 7;
  #pragma unroll
  for (int j = 0; j < 8; ++j){ int a = padi(q*64 + n + 8*j); v[j].x = re[a]; v[j].y = im[a]; }
  fft8(v);
  twiddle8(v, TW * (float)n * (1.0f/64.0f));
  lds_fence();
  #pragma unroll
  for (int m = 0; m < 8; ++m){ int a = padi(q*64 + m*8 + n); re[a] = v[m].x; im[a] = v[m].y; }
  lds_fence();
  #pragma unroll
  for (int j = 0; j < 8; ++j){ int a = padi(q*64 + n*8 + j); v[j].x = re[a]; v[j].y = im[a]; }
  fft8(v);
}

#define GRAY1(r,g,b) ((fmaf(0.299f,(r), fmaf(0.587f,(g), 0.114f*(b))) + 1.0f)*0.5f)

// Issue 12 x 1KB direct-to-LDS DMA for one row pair (3 channels x 4 segs).
__device__ __forceinline__ void dma_pair(const float* base, float* st, int t){
  #pragma unroll
  for (int ch = 0; ch < 3; ++ch){
    const float* pb = base + ch * 262144 + 4*t;
    float* lb = st + ch*1024;
    #pragma unroll
    for (int seg = 0; seg < 4; ++seg){
      __builtin_amdgcn_global_load_lds(
        (const __attribute__((address_space(1))) void*)(pb + seg*256),
        (__attribute__((address_space(3))) void*)(lb + seg*256),
        16, 0, 0);
    }
  }
}

// Stage 1: pipelined packed row-pair FFTs. Block 128 = 2 waves; 8 pairs/wave,
// double-buffered staging (24KB/wave). Grid = nimg * 16.
// ws: [img_local][pair][kx] half2, TRUE frequency order.
__global__ __launch_bounds__(128)
void k_rowfft(const float* __restrict__ gen, const float* __restrict__ tgt,
              __half2* ws, int img0){
  __half2* w = ws ? ws : g_wsfall;
  const int wg   = blockIdx.x;
  const int imgl = wg >> 4;
  const int bl   = wg & 15;
  const int img  = img0 + imgl;
  const int wave = threadIdx.x >> 6, t = threadIdx.x & 63;
  const int prB  = bl*16 + wave*8;               // first of 8 pairs
  const float* src = (img < 32) ? gen : tgt;
  const float* base0 = src + (size_t)(img & 31) * 786432 + (size_t)prB * 1024;

  // [wave][buf] 12KB staging; buf[n&1] holds pair n, reused as FFT exchange
  // (re = [0,576), im = [1024,1600)) after gray is consumed into registers.
  __shared__ float stage_all[2][2][3072];
  float* stg0 = stage_all[wave][0];
  float* stg1 = stage_all[wave][1];

  const int off = 8*(t & 7) + (t >> 3);

  dma_pair(base0, stg0, t);                      // prologue: pair 0 in flight
  #pragma unroll
  for (int n = 0; n < 8; ++n){
    float* stc = (n & 1) ? stg1 : stg0;
    float* stn = (n & 1) ? stg0 : stg1;
    // ensure prior FFT's exchange reads (in stn) are drained before DMA
    lds_fence();
    if (n < 7) dma_pair(base0 + (size_t)(n+1)*1024, stn, t);
    // wait for DMA(n): 12 oldest ops.  Younger in flight:
    //   stores(n-1) x8 (n>=1) + DMA(n+1) x12 (n<7)  -> counted, never 0.
    if (n == 0)      { asm volatile("s_waitcnt vmcnt(12)" ::: "memory"); }
    else if (n < 7)  { asm volatile("s_waitcnt vmcnt(20)" ::: "memory"); }
    else             { asm volatile("s_waitcnt vmcnt(8)"  ::: "memory"); }
    __builtin_amdgcn_sched_barrier(0);

    // Gray from LDS (stride-1 b32 reads, conflict-free).
    float2 v[8];
    #pragma unroll
    for (int j = 0; j < 8; ++j){
      const int x = t + 64*j;
      v[j] = make_float2(GRAY1(stc[x],     stc[1024+x], stc[2048+x]),
                         GRAY1(stc[512+x], stc[1536+x], stc[2560+x]));
    }
    fft512(v, stc, stc + 1024, t);

    // Store fp16, TRUE frequency order: reg j -> kx = 64j + off.
    __half2* dst = w + ((size_t)imgl * 256 + (prB + n)) * 512;
    #pragma unroll
    for (int j = 0; j < 8; ++j) dst[64*j + off] = __floats2half2_rn(v[j].x, v[j].y);
  }
}

// Stage 2: column FFTs for kx = 0..256 + masked log10 reduction.
// Blocks 0..31: kx = 8g..8g+7 (2 cols/wave). Block 32: kx=256 (wave 0 only).
// Grid = nimg * 33.
__global__ __launch_bounds__(256)
void k_colfft(const __half2* __restrict__ ws, int img0){
  const __half2* w = ws ? ws : (const __half2*)g_wsfall;
  const int wg   = blockIdx.x;
  const int imgl = wg / 33;
  const int blk  = wg - imgl * 33;
  const int img  = img0 + imgl;
  const int kx0  = blk * 8;
  const int tid  = threadIdx.x;
  const int wave = tid >> 6, t = tid & 63;
  const int ncols = (blk == 32) ? 1 : 8;

  __shared__ float2 own[8][260], mir[8][260];
  __shared__ float re_all[4][576], im_all[4][576];
  float* re = re_all[wave];
  float* im = im_all[wave];

  const __half2* zb = w + (size_t)imgl * 131072;    // 256 pairs * 512
  #pragma unroll
  for (int it = 0; it < 8; ++it){
    const int idx = it*256 + tid;                   // 0..2047
    const int p = idx >> 3, e = idx & 7;
    own[e][p] = __half22float2(zb[p*512 + kx0 + e]);
    mir[e][p] = __half22float2(zb[p*512 + ((512 - (kx0 + e)) & 511)]);
  }
  __syncthreads();

  double acc = 0.0;
  for (int ci = 0; ci < 2; ++ci){
    const int e = wave*2 + ci;
    if (e < ncols){
      const int kx = kx0 + e;
      const bool sub_own = (kx <= 63);              // lowband(kx), kx in 0..256
      const bool sub_mir = (kx >= 1) & (kx <= 64);  // lowband(512-kx)
      const float base = (kx == 0 || kx == 256) ? 1.0f : 2.0f;

      float2 v[8];
      const int u = t >> 1;
      const bool odd = (t & 1);
      #pragma unroll
      for (int j = 0; j < 8; ++j){
        const int p = u + 32*j;
        float2 A = own[e][p];
        float2 B = mir[e][p]; B.y = -B.y;           // conj
        float2 Fe = make_float2((A.x + B.x)*0.5f, (A.y + B.y)*0.5f);
        float2 Fo = mul_mi(make_float2((A.x - B.x)*0.5f, (A.y - B.y)*0.5f));
        v[j] = odd ? Fo : Fe;
      }
      fft512(v, re, im, t);

      #pragma unroll
      for (int j = 0; j < 8; ++j){
        const bool inS  = (j == 0) | (j == 7);
        const bool inSp = (j == 0) | ((j == 1) & (t == 0)) | ((j == 7) & (t != 0));
        float wgt = base;
        if (sub_own & inS)  wgt -= 1.0f;
        if (sub_mir & inSp) wgt -= 1.0f;
        float m2 = fmaf(v[j].x, v[j].x, fmaf(v[j].y, v[j].y, 1e-10f));
        acc += (double)wgt * (double)log10f(m2);
      }
    }
  }
  #pragma unroll
  for (int off = 32; off; off >>= 1) acc += __shfl_down(acc, off);
  if (t == 0) g_partials[((size_t)img * 33 + blk) * 4 + wave] = acc;
}

// Final: psd per image, L1 over batch.
__global__ __launch_bounds__(256)
void k_finish(float* __restrict__ out){
  const int tid = threadIdx.x;
  const int img = tid >> 2, part = tid & 3;
  const double* p = g_partials + (size_t)img * 132 + part;
  double s = 0.0;
  for (int k = 0; k < 33; ++k) s += p[4*k];
  __shared__ double sm[256];
  sm[tid] = s;
  __syncthreads();
  if ((tid & 3) == 0){
    double tot = sm[tid] + sm[tid+1] + sm[tid+2] + sm[tid+3];
    sm[tid] = tot * (1.0 / 245760.0);          // psd[img]
  }
  __syncthreads();
  if (tid < 64){
    double dv = (tid < 32) ? fabs(sm[tid*4] - sm[(tid+32)*4]) : 0.0;
    #pragma unroll
    for (int off = 32; off; off >>= 1) dv += __shfl_down(dv, off);
    if (tid == 0) out[0] = (float)(dv * (1.0 / 32.0));
  }
}

extern "C" void kernel_launch(void* const* d_in, const int* in_sizes, int n_in,
                              void* d_out, int out_size, void* d_ws, size_t ws_size,
                              hipStream_t stream){
  (void)in_sizes; (void)n_in; (void)out_size;
  const float* gen = (const float*)d_in[0];
  const float* tgt = (const float*)d_in[1];
  float* out = (float*)d_out;

  const size_t per_img = (size_t)256 * 512 * sizeof(__half2);  // 512 KiB
  int chunk = (int)(ws_size / per_img);
  __half2* wsp = (__half2*)d_ws;
  if (chunk < 1){ chunk = 1; wsp = nullptr; }   // static 1-image fallback
  if (chunk > 64) chunk = 64;

  for (int i0 = 0; i0 < 64; i0 += chunk){
    const int n = (64 - i0 < chunk) ? (64 - i0) : chunk;
    k_rowfft<<<dim3(n * 16), dim3(128), 0, stream>>>(gen, tgt, wsp, i0);
    k_colfft<<<dim3(n * 33), dim3(256), 0, stream>>>(wsp, i0);
  }
  k_finish<<<dim3(1), dim3(256), 0, stream>>>(out);
}

// Round 8
// 70.529 us; speedup vs baseline: 1.6949x; 1.0270x over previous
//
#include <hip/hip_runtime.h>
#include <hip/hip_bf16.h>
#include <hip/hip_fp16.h>
#include <math.h>

// ---------------------------------------------------------------------------
// HighFreqSuppressionLoss, real-packed rows + Hermitian-halved columns.
// gray = (0.299R+0.587G+0.114B+1)/2; F = fft2(gray);
// loss = mean_b | mean_M log10(|F_gen|^2+eps) - mean_M log10(|F_tgt|^2+eps) |
// Mask excludes (kx,ky) iff lowband(kx)&&lowband(ky); lowband: k<64||k>=448.
//
// Stage 1 (pipelined): pack rows (2p,2p+1) as z = a+ib, one 512-pt FFT/pair.
//   8 pairs/wave, double-buffered LDS-DMA staging, counted vmcnt (never 0
//   mid-loop).  Z stored fp16 in TRUE FREQUENCY ORDER into a static 32MB
//   device buffer: ws[img][pair][kx], kx = 64j + 8(t&7) + (t>>3).
// Stage 2: 16 columns per block (64B-sector-aligned stripe reads, own+mirror),
//   kx = 0..256 only; element weight base = (kx==0||kx==256)?1:2,
//   minus [kx<=63]*[ky in S], minus [1<=kx<=64]*[ky in S'];
//   S <=> j==0||j==7;  S' <=> j==0 || (j==1&&t==0) || (j==7&&t!=0).
//   (weights total 245760; logic identical to passing R4-R7 kernels)
// ---------------------------------------------------------------------------

__device__ double g_partials[64 * 17 * 4];                   // [img][blk][wave]
__device__ __align__(16) __half2 g_ws[(size_t)64 * 256 * 512];  // 32 MiB

__device__ __forceinline__ float2 cadd(float2 a, float2 b){ return make_float2(a.x+b.x, a.y+b.y); }
__device__ __forceinline__ float2 csub(float2 a, float2 b){ return make_float2(a.x-b.x, a.y-b.y); }
__device__ __forceinline__ float2 cmul(float2 a, float2 b){
  return make_float2(fmaf(a.x, b.x, -(a.y*b.y)), fmaf(a.x, b.y, a.y*b.x));
}
__device__ __forceinline__ float2 mul_mi(float2 a){ return make_float2(a.y, -a.x); } // *(-i)

__device__ __forceinline__ void fft8(float2 v[8]){
  const float S = 0.70710678118654752440f;
  float2 c0=cadd(v[0],v[4]), c1=cadd(v[1],v[5]), c2=cadd(v[2],v[6]), c3=cadd(v[3],v[7]);
  float2 d0=csub(v[0],v[4]);
  float2 t1=csub(v[1],v[5]);
  float2 d1=make_float2(S*(t1.x+t1.y), S*(t1.y-t1.x));   // *w8^1
  float2 d2=mul_mi(csub(v[2],v[6]));                     // *w8^2
  float2 t3=csub(v[3],v[7]);
  float2 d3=make_float2(S*(t3.y-t3.x), -S*(t3.x+t3.y));  // *w8^3
  float2 e0=cadd(c0,c2), e1=cadd(c1,c3), f0=csub(c0,c2), f1=mul_mi(csub(c1,c3));
  float2 g0=cadd(d0,d2), g1=cadd(d1,d3), h0=csub(d0,d2), h1=mul_mi(csub(d1,d3));
  v[0]=cadd(e0,e1); v[4]=csub(e0,e1);
  v[2]=cadd(f0,f1); v[6]=csub(f0,f1);
  v[1]=cadd(g0,g1); v[5]=csub(g0,g1);
  v[3]=cadd(h0,h1); v[7]=csub(h0,h1);
}

__device__ __forceinline__ void twiddle8(float2 v[8], float ang){
  float sn, cs;
  __sincosf(ang, &sn, &cs);
  float2 w = make_float2(cs, sn);
  float2 wp = w;
  v[1] = cmul(v[1], wp);
  #pragma unroll
  for (int m = 2; m < 8; ++m){ wp = cmul(wp, w); v[m] = cmul(v[m], wp); }
}

__device__ __forceinline__ int padi(int i){ return i + (i >> 3); }

// Wave-internal LDS fence (exchange is intra-wave; no block barrier needed).
__device__ __forceinline__ void lds_fence(){
  asm volatile("s_waitcnt lgkmcnt(0)" ::: "memory");
  __builtin_amdgcn_sched_barrier(0);
}

// 512-pt DIF FFT across one wave. Lane t holds x[t+64j] on entry.
// Exit: reg j of lane t = stored s = 8t+j, true freq 64j + 8(t&7) + (t>>3).
__device__ __forceinline__ void fft512(float2 v[8], float* re, float* im, int t){
  const float TW = -6.28318530717958647692f;
  fft8(v);
  twiddle8(v, TW * (float)t * (1.0f/512.0f));
  lds_fence();
  #pragma unroll
  for (int m = 0; m < 8; ++m){ int a = padi(m*64 + t); re[a] = v[m].x; im[a] = v[m].y; }
  lds_fence();
  const int q = t >> 3, n = t & 7;
  #pragma unroll
  for (int j = 0; j < 8; ++j){ int a = padi(q*64 + n + 8*j); v[j].x = re[a]; v[j].y = im[a]; }
  fft8(v);
  twiddle8(v, TW * (float)n * (1.0f/64.0f));
  lds_fence();
  #pragma unroll
  for (int m = 0; m < 8; ++m){ int a = padi(q*64 + m*8 + n); re[a] = v[m].x; im[a] = v[m].y; }
  lds_fence();
  #pragma unroll
  for (int j = 0; j < 8; ++j){ int a = padi(q*64 + n*8 + j); v[j].x = re[a]; v[j].y = im[a]; }
  fft8(v);
}

#define GRAY1(r,g,b) ((fmaf(0.299f,(r), fmaf(0.587f,(g), 0.114f*(b))) + 1.0f)*0.5f)

// Issue 12 x 1KB direct-to-LDS DMA for one row pair (3 channels x 4 segs).
__device__ __forceinline__ void dma_pair(const float* base, float* st, int t){
  #pragma unroll
  for (int ch = 0; ch < 3; ++ch){
    const float* pb = base + ch * 262144 + 4*t;
    float* lb = st + ch*1024;
    #pragma unroll
    for (int seg = 0; seg < 4; ++seg){
      __builtin_amdgcn_global_load_lds(
        (const __attribute__((address_space(1))) void*)(pb + seg*256),
        (__attribute__((address_space(3))) void*)(lb + seg*256),
        16, 0, 0);
    }
  }
}

// Stage 1: pipelined packed row-pair FFTs. Block 128 = 2 waves; 8 pairs/wave,
// double-buffered staging (24KB/wave). Grid = 64 * 16.
__global__ __launch_bounds__(128)
void k_rowfft(const float* __restrict__ gen, const float* __restrict__ tgt){
  const int wg   = blockIdx.x;
  const int img  = wg >> 4;
  const int bl   = wg & 15;
  const int wave = threadIdx.x >> 6, t = threadIdx.x & 63;
  const int prB  = bl*16 + wave*8;               // first of 8 pairs
  const float* src = (img < 32) ? gen : tgt;
  const float* base0 = src + (size_t)(img & 31) * 786432 + (size_t)prB * 1024;

  // [wave][buf] 12KB staging; buf[n&1] holds pair n, reused as FFT exchange
  // (re = [0,576), im = [1024,1600)) after gray is consumed into registers.
  __shared__ float stage_all[2][2][3072];
  float* stg0 = stage_all[wave][0];
  float* stg1 = stage_all[wave][1];

  const int off = 8*(t & 7) + (t >> 3);

  dma_pair(base0, stg0, t);                      // prologue: pair 0 in flight
  #pragma unroll
  for (int n = 0; n < 8; ++n){
    float* stc = (n & 1) ? stg1 : stg0;
    float* stn = (n & 1) ? stg0 : stg1;
    // ensure prior FFT's exchange reads (in stn) are drained before DMA
    lds_fence();
    if (n < 7) dma_pair(base0 + (size_t)(n+1)*1024, stn, t);
    // wait for DMA(n): 12 oldest ops.  Younger in flight:
    //   stores(n-1) x8 (n>=1) + DMA(n+1) x12 (n<7)  -> counted, never 0.
    if (n == 0)      { asm volatile("s_waitcnt vmcnt(12)" ::: "memory"); }
    else if (n < 7)  { asm volatile("s_waitcnt vmcnt(20)" ::: "memory"); }
    else             { asm volatile("s_waitcnt vmcnt(8)"  ::: "memory"); }
    __builtin_amdgcn_sched_barrier(0);

    // Gray from LDS (stride-1 b32 reads, conflict-free).
    float2 v[8];
    #pragma unroll
    for (int j = 0; j < 8; ++j){
      const int x = t + 64*j;
      v[j] = make_float2(GRAY1(stc[x],     stc[1024+x], stc[2048+x]),
                         GRAY1(stc[512+x], stc[1536+x], stc[2560+x]));
    }
    fft512(v, stc, stc + 1024, t);

    // Store fp16, TRUE frequency order: reg j -> kx = 64j + off.
    __half2* dst = g_ws + ((size_t)img * 256 + (prB + n)) * 512;
    #pragma unroll
    for (int j = 0; j < 8; ++j) dst[64*j + off] = __floats2half2_rn(v[j].x, v[j].y);
  }
}

// Stage 2: column FFTs for kx = 0..256 + masked log10 reduction.
// Blocks g=0..15: 16 cols kx=16g..16g+15 (4 cols/wave serially).
// Block g=16: kx=256 only (wave 0, ci 0). Grid = 64 * 17.
// Stripe reads are 64B/row sector-aligned chunks (own and mirror).
__global__ __launch_bounds__(256)
void k_colfft(){
  const int wg   = blockIdx.x;
  const int img  = wg / 17;
  const int blk  = wg - img * 17;
  const int kx0  = blk * 16;
  const int tid  = threadIdx.x;
  const int wave = tid >> 6, t = tid & 63;
  const int ncols = (blk == 16) ? 1 : 16;

  // raw half2 tiles, pad 258: load-writes <=2-way, col reads broadcast-free
  __shared__ __half2 own[16 * 258], mir[16 * 258];
  __shared__ float re_all[4][576], im_all[4][576];
  float* re = re_all[wave];
  float* im = im_all[wave];

  const __half2* zb = g_ws + (size_t)img * 131072;  // 256 pairs * 512
  #pragma unroll
  for (int it = 0; it < 16; ++it){
    const int idx = it*256 + tid;                   // 0..4095
    const int p = idx >> 4, e = idx & 15;
    own[e*258 + p] = zb[p*512 + kx0 + e];
    mir[e*258 + p] = zb[p*512 + ((512 - (kx0 + e)) & 511)];
  }
  __syncthreads();

  double acc = 0.0;
  for (int ci = 0; ci < 4; ++ci){
    const int e = wave*4 + ci;
    if (e < ncols){
      const int kx = kx0 + e;
      const bool sub_own = (kx <= 63);              // lowband(kx), kx in 0..256
      const bool sub_mir = (kx >= 1) & (kx <= 64);  // lowband(512-kx)
      const float base = (kx == 0 || kx == 256) ? 1.0f : 2.0f;

      float2 v[8];
      const int u = t >> 1;
      const bool odd = (t & 1);
      #pragma unroll
      for (int j = 0; j < 8; ++j){
        const int p = u + 32*j;
        float2 A = __half22float2(own[e*258 + p]);
        float2 B = __half22float2(mir[e*258 + p]); B.y = -B.y;   // conj
        float2 Fe = make_float2((A.x + B.x)*0.5f, (A.y + B.y)*0.5f);
        float2 Fo = mul_mi(make_float2((A.x - B.x)*0.5f, (A.y - B.y)*0.5f));
        v[j] = odd ? Fo : Fe;
      }
      fft512(v, re, im, t);

      #pragma unroll
      for (int j = 0; j < 8; ++j){
        const bool inS  = (j == 0) | (j == 7);
        const bool inSp = (j == 0) | ((j == 1) & (t == 0)) | ((j == 7) & (t != 0));
        float wgt = base;
        if (sub_own & inS)  wgt -= 1.0f;
        if (sub_mir & inSp) wgt -= 1.0f;
        float m2 = fmaf(v[j].x, v[j].x, fmaf(v[j].y, v[j].y, 1e-10f));
        acc += (double)wgt * (double)log10f(m2);
      }
    }
  }
  #pragma unroll
  for (int off = 32; off; off >>= 1) acc += __shfl_down(acc, off);
  if (t == 0) g_partials[((size_t)img * 17 + blk) * 4 + wave] = acc;
}

// Final: psd per image, L1 over batch.
__global__ __launch_bounds__(256)
void k_finish(float* __restrict__ out){
  const int tid = threadIdx.x;
  const int img = tid >> 2, part = tid & 3;
  const double* p = g_partials + (size_t)img * 68 + part;
  double s = 0.0;
  for (int k = 0; k < 17; ++k) s += p[4*k];
  __shared__ double sm[256];
  sm[tid] = s;
  __syncthreads();
  if ((tid & 3) == 0){
    double tot = sm[tid] + sm[tid+1] + sm[tid+2] + sm[tid+3];
    sm[tid] = tot * (1.0 / 245760.0);          // psd[img]
  }
  __syncthreads();
  if (tid < 64){
    double dv = (tid < 32) ? fabs(sm[tid*4] - sm[(tid+32)*4]) : 0.0;
    #pragma unroll
    for (int off = 32; off; off >>= 1) dv += __shfl_down(dv, off);
    if (tid == 0) out[0] = (float)(dv * (1.0 / 32.0));
  }
}

extern "C" void kernel_launch(void* const* d_in, const int* in_sizes, int n_in,
                              void* d_out, int out_size, void* d_ws, size_t ws_size,
                              hipStream_t stream){
  (void)in_sizes; (void)n_in; (void)out_size; (void)d_ws; (void)ws_size;
  const float* gen = (const float*)d_in[0];
  const float* tgt = (const float*)d_in[1];
  float* out = (float*)d_out;

  k_rowfft<<<dim3(64 * 16), dim3(128), 0, stream>>>(gen, tgt);
  k_colfft<<<dim3(64 * 17), dim3(256), 0, stream>>>();
  k_finish<<<dim3(1), dim3(256), 0, stream>>>(out);
}